// Round 13
// baseline (379.234 us; speedup 1.0000x reference)
//
#include <hip/hip_runtime.h>
#include <math.h>

// NerfHead: fused ray-march + trilinear + online transmittance + 3 losses.
// R12 = R6 main body VERBATIM (best-measured family: R1=234/R6=248/R8=232us;
//       three structures converge ~240us, FETCH pinned 39MB -> scattered-VMEM
//       plateau) + single-launch packaging:
//   - hipMemsetAsync zeroes bins+done-counter (516B; capture-legal)
//   - fused finalize: last block computes outputs (threadfence + atomic reads)
//   - t-table: per-block f64 (as R6; ~1us amortized)
//   R9 lesson: span-loads + gather-reorder dropped VGPR 76->52 and serialized
//   load chains (VALUBusy 27->21, dur +25%) -> REVERTED. The limiting resource
//   is per-wave MLP; R6's flat 8-corner gather keeps ~40 loads in flight.
//   Launch overhead ~24us/launch measured (R1/R6/R9 total-main deltas);
//   3 launches -> 1 launch + memset harvests ~45us.
// d_ws: floats [0..127] = 8 bins x 16 stride; int at byte 512 = done counter.

#define DXX 200
#define DYY 200
#define DZZ 16
#define NC 17
#define S_TOT 416
#define N_IN 390
#define CHUNKS 7
#define NBINS 8
#define BINSTRIDE 16
#define CNT_OFF 128   // int index of done-counter (byte 512)

typedef float v4u __attribute__((ext_vector_type(4), aligned(4), may_alias));
typedef float v2u __attribute__((ext_vector_type(2), aligned(4), may_alias));

__constant__ double c_freq[NC] = {1163161.0, 2309034.0, 188743.0, 2997643.0,
  20317180.0, 852476.0, 243808.0, 2457947.0, 497017.0, 2731022.0, 7224789.0,
  214411435.0, 5565043.0, 63191967.0, 76098082.0, 128860031.0, 141625221.0};

__device__ __forceinline__ float iscan_add(float x, int lane) {
#pragma unroll
  for (int off = 1; off < 64; off <<= 1) {
    float y = __shfl_up(x, off);
    if (lane >= off) x += y;
  }
  return x;
}
__device__ __forceinline__ float iscan_mul(float x, int lane) {
#pragma unroll
  for (int off = 1; off < 64; off <<= 1) {
    float y = __shfl_up(x, off);
    if (lane >= off) x *= y;
  }
  return x;
}

__global__ __launch_bounds__(64) void nerf_main(
    const float* __restrict__ density,
    const float* __restrict__ semantic,
    const float* __restrict__ rays,
    const float* __restrict__ bda,
    float* __restrict__ acc_g,
    float* __restrict__ out,
    int nrays) {
  __shared__ float s_t[CHUNKS * 64];
  __shared__ float s_dist[S_TOT];
  __shared__ unsigned long long s_keep[CHUNKS];
  __shared__ unsigned long long s_big[CHUNKS];

  const int lane = threadIdx.x;
  const int ray = blockIdx.x;

  // ---- constants matching the reference's numpy derivations ----
  const double BG = (double)(1.0f / 39.0f);
  const float BGf = (float)BG;
  const float DTH = (float)((2.0 + 2.0 * BG) / 200.0 * 0.5 * 0.95);
  const float xminf = (float)(-1.0 - BG);
  const float zf = 6.4f / 80.0f;
  const float sxy = 199.0f / ((float)(1.0 + BG) - xminf);
  const float szc = 15.0f / (zf + zf);
  const float ACTS = -13.815509557964274f;

  const float* rp = rays + (size_t)ray * 10;
  float dep = rp[2];
  bool valid = (ray < nrays) && (dep > 0.f) && (dep <= 52.f);

  if (valid) {
    int ysem = (int)rp[3];
    ysem = ysem < 0 ? 0 : (ysem > NC - 1 ? NC - 1 : ysem);
    const float czc = (-1.0f + 5.4f) * 0.5f;
    float rox = rp[4] / 39.0f;
    float roy = rp[5] / 39.0f;
    float roz = (rp[6] - czc) / 39.0f;
    float d0 = rp[7], d1 = rp[8], d2 = rp[9];
    float rn = sqrtf(d0 * d0 + d1 * d1 + d2 * d2);
    float rdx = d0 / rn, rdy = d1 / rn, rdz = d2 / rn;

    // ---- t table (wave-private; 7 iterations per lane; f64 as reference) --
    for (int i = lane; i < CHUNKS * 64; i += 64) {
      double td;
      if (i < N_IN) {
        td = (2.0 * i + 1.0) / 390.0;
      } else {
        int j = i - N_IN;
        const double stp = (1.0 / 64.0 - 1.0) / 26.0;
        double l0 = 1.0 + j * stp;
        double l1 = (j + 1 >= 26) ? (1.0 / 64.0) : (1.0 + (j + 1) * stp);
        td = 1.0 / l0 + 1.0 / l1;
      }
      s_t[i] = (float)td;
    }
    asm volatile("s_waitcnt lgkmcnt(0)" ::: "memory");

    const float b00 = bda[0], b01 = bda[1], b02 = bda[2];
    const float b10 = bda[3], b11 = bda[4], b12 = bda[5];
    const float b20 = bda[6], b21 = bda[7], b22 = bda[8];

    auto compute_pt = [&](int s, float& tx, float& ty, float& tz, float& tt,
                          bool& inner) {
      tt = s_t[s];
      float qx = rox + rdx * tt;
      float qy = roy + rdy * tt;
      float qz = roz + rdz * tt;
      float nr = sqrtf(qx * qx + qy * qy + qz * qz);
      inner = (nr <= 1.0f) && (s < S_TOT);
      if (nr > 1.0f) {
        float sc = (1.0f + BGf - BGf / nr) / nr;
        qx *= sc; qy *= sc; qz *= sc;
      }
      tx = b00 * qx + b01 * qy + b02 * qz;
      ty = b10 * qx + b11 * qy + b12 * qz;
      tz = b20 * qx + b21 * qy + b22 * qz;
    };

    // ---- phase A/B: pts, inner+big ballots, consecutive distances -> LDS --
    for (int c = 0; c < CHUNKS; c++) {
      int s = c * 64 + lane;
      float tx, ty, tz, tt; bool inner;
      compute_pt(s, tx, ty, tz, tt, inner);
      unsigned long long bal = __ballot(inner);
      float nx = __shfl(tx, lane + 1);
      float ny = __shfl(ty, lane + 1);
      float nz = __shfl(tz, lane + 1);
      if (c < CHUNKS - 1) {
        float hx, hy, hz, ht; bool hi;
        compute_pt((c + 1) * 64, hx, hy, hz, ht, hi);
        if (lane == 63) { nx = hx; ny = hy; nz = hz; }
      }
      float ex = nx - tx, ey = ny - ty, ez = nz - tz;
      float dd = sqrtf(ex * ex + ey * ey + ez * ez);
      bool dlive = (s < S_TOT - 1);
      if (dlive) s_dist[s] = dd;
      unsigned long long db = __ballot(dlive && (dd > DTH));
      if (lane == 0) { s_keep[c] = bal; s_big[c] = db; }
    }

    // ---- phase C: resetting distance scan, serial ONLY over non-big steps.
    // big step (dist > DTH) forces over=1, cum=0 regardless of incoming cum
    // (f32 add of non-negatives is monotone) -> bit-exact decomposition.
    asm volatile("s_waitcnt lgkmcnt(0)" ::: "memory");
    if (lane == 0) {
      float cum = 0.f;
      int prev = 0;
      unsigned long long carrybit = 0;
#pragma unroll
      for (int c = 0; c < CHUNKS; c++) {
        unsigned long long inner = s_keep[c];
        unsigned long long db = s_big[c];
        unsigned long long big = (db << 1) | carrybit;
        carrybit = db >> 63;
        unsigned long long vmask = ~0ull;
        if (c == 0) vmask &= ~1ull;                       // s=0 is not a step
        if (c == CHUNKS - 1) vmask &= 0x00000000FFFFFFFFull;  // s<=415
        big &= vmask;
        unsigned long long k = inner | big;
        unsigned long long nb = vmask & ~big;
        while (nb) {
          int b = __ffsll((unsigned long long)nb) - 1;
          nb &= nb - 1;
          int s = c * 64 + b;
          if (s - 1 != prev) cum = 0.f;  // gap => previous step was big
          cum += s_dist[s - 1];
          if (cum > DTH) { cum = 0.f; k |= 1ull << b; }
          prev = s;
        }
        s_keep[c] = k;
      }
    }
    asm volatile("s_waitcnt lgkmcnt(0)" ::: "memory");

    // ---- phase D/E/F merged: density->alpha, scans, semantic (one loop) --
    float out_sem[NC];
#pragma unroll
    for (int j = 0; j < NC; j++) out_sem[j] = 0.f;
    float carry = 1.f, carryW = 0.f, carryWM = 0.f;
    float sum_bi = 0.f, sum_w2 = 0.f, pkcf = 0.f;

    for (int c = 0; c < CHUNKS; c++) {
      unsigned long long km = s_keep[c];
      if (km == 0ull) continue;  // exact identity: a==0 => carries unchanged
      int s = c * 64 + lane;
      float tx, ty, tz, tt; bool inner;
      compute_pt(s, tx, ty, tz, tt, inner);
      float m_ = 1.0f - 1.0f / (1.0f + tt);
      bool keep = (km >> lane) & 1ull;

      float gx = (tx - xminf) * sxy;
      float gy = (ty - xminf) * sxy;
      float gz = (tz + zf) * szc;
      float hxf = floorf(gx), hyf = floorf(gy), hzf = floorf(gz);
      int ix = (int)hxf, iy = (int)hyf, iz = (int)hzf;
      float fx = gx - hxf, fy = gy - hyf, fz = gz - hzf;
      float wx0 = 1.f - fx, wy0 = 1.f - fy, wz0 = 1.f - fz;
      bool vx0 = (unsigned)ix < (unsigned)DXX, vx1 = (unsigned)(ix + 1) < (unsigned)DXX;
      bool vy0 = (unsigned)iy < (unsigned)DYY, vy1 = (unsigned)(iy + 1) < (unsigned)DYY;
      bool vz0 = (unsigned)iz < (unsigned)DZZ, vz1 = (unsigned)(iz + 1) < (unsigned)DZZ;

      float a = 0.f;
      if (keep) {
        float dens = 0.f;
        const float* p0 = density + (ix * DYY + iy) * DZZ + iz;
        if (vx0 && vx1 && vy0 && vy1 && vz0 && vz1) {
          v2u d00 = *(const v2u*)(p0);
          v2u d01 = *(const v2u*)(p0 + DZZ);
          v2u d10 = *(const v2u*)(p0 + DYY * DZZ);
          v2u d11 = *(const v2u*)(p0 + DYY * DZZ + DZZ);
          dens += wx0 * wy0 * wz0 * d00[0];
          dens += wx0 * wy0 * fz  * d00[1];
          dens += wx0 * fy  * wz0 * d01[0];
          dens += wx0 * fy  * fz  * d01[1];
          dens += fx  * wy0 * wz0 * d10[0];
          dens += fx  * wy0 * fz  * d10[1];
          dens += fx  * fy  * wz0 * d11[0];
          dens += fx  * fy  * fz  * d11[1];
        } else {
          if (vx0 && vy0 && vz0) dens += wx0 * wy0 * wz0 * p0[0];
          if (vx0 && vy0 && vz1) dens += wx0 * wy0 * fz  * p0[1];
          if (vx0 && vy1 && vz0) dens += wx0 * fy  * wz0 * p0[DZZ];
          if (vx0 && vy1 && vz1) dens += wx0 * fy  * fz  * p0[DZZ + 1];
          if (vx1 && vy0 && vz0) dens += fx  * wy0 * wz0 * p0[DYY * DZZ];
          if (vx1 && vy0 && vz1) dens += fx  * wy0 * fz  * p0[DYY * DZZ + 1];
          if (vx1 && vy1 && vz0) dens += fx  * fy  * wz0 * p0[DYY * DZZ + DZZ];
          if (vx1 && vy1 && vz1) dens += fx  * fy  * fz  * p0[DYY * DZZ + DZZ + 1];
        }
        float u = expf(dens + ACTS);
        a = -expm1f(-0.5f * log1pf(u));  // 1-(1+u)^-0.5, no cancellation
        if (!(a > 1e-7f)) a = 0.f;
      }

      // transmittance cumprod (chunked scan + carry)
      float om = 1.f - a;
      float ip = iscan_mul(om, lane);
      float ex = __shfl_up(ip, 1); if (lane == 0) ex = 1.f;
      float wgt = a * carry * ex;
      carry *= __shfl(ip, 63);
      float w = (wgt > 1e-7f) ? wgt : 0.f;
      if (w > 0.f) pkcf += 1.f;

      // distortion-loss cumsums (exclusive)
      float wm = w * m_;
      float isw = iscan_add(w, lane);
      float iswm = iscan_add(wm, lane);
      float exw = __shfl_up(isw, 1);  if (lane == 0) exw = 0.f;
      float exwm = __shfl_up(iswm, 1); if (lane == 0) exwm = 0.f;
      sum_bi += 2.f * w * (m_ * (carryW + exw) - (carryWM + exwm));
      sum_w2 += w * w;
      carryW += __shfl(isw, 63);
      carryWM += __shfl(iswm, 63);

      // semantic trilinear, only where weight survives (w>0 implies keep)
      if (w > 0.f) {
        const float* sp0 = semantic + (size_t)((ix * DYY + iy) * DZZ + iz) * NC;
        const float* sp1 = sp0 + DYY * DZZ * NC;
#define SEM_ACC(PTR, WC)                                                        \
        { float wc = (WC);                                                      \
          const v4u* q = (const v4u*)(PTR);                                     \
          v4u q0 = q[0], q1 = q[1], q2 = q[2], q3 = q[3];                       \
          float qs = (PTR)[16];                                                 \
          out_sem[0]  += wc * q0[0];  out_sem[1]  += wc * q0[1];                \
          out_sem[2]  += wc * q0[2];  out_sem[3]  += wc * q0[3];                \
          out_sem[4]  += wc * q1[0];  out_sem[5]  += wc * q1[1];                \
          out_sem[6]  += wc * q1[2];  out_sem[7]  += wc * q1[3];                \
          out_sem[8]  += wc * q2[0];  out_sem[9]  += wc * q2[1];                \
          out_sem[10] += wc * q2[2];  out_sem[11] += wc * q2[3];                \
          out_sem[12] += wc * q3[0];  out_sem[13] += wc * q3[1];                \
          out_sem[14] += wc * q3[2];  out_sem[15] += wc * q3[3];                \
          out_sem[16] += wc * qs; }
        if (vx0 && vx1 && vy0 && vy1 && vz0 && vz1) {
          SEM_ACC(sp0,                 w * wx0 * wy0 * wz0)
          SEM_ACC(sp0 + NC,            w * wx0 * wy0 * fz)
          SEM_ACC(sp0 + DZZ * NC,      w * wx0 * fy  * wz0)
          SEM_ACC(sp0 + DZZ * NC + NC, w * wx0 * fy  * fz)
          SEM_ACC(sp1,                 w * fx  * wy0 * wz0)
          SEM_ACC(sp1 + NC,            w * fx  * wy0 * fz)
          SEM_ACC(sp1 + DZZ * NC,      w * fx  * fy  * wz0)
          SEM_ACC(sp1 + DZZ * NC + NC, w * fx  * fy  * fz)
        } else {
          if (vx0 && vy0 && vz0) SEM_ACC(sp0,                 w * wx0 * wy0 * wz0)
          if (vx0 && vy0 && vz1) SEM_ACC(sp0 + NC,            w * wx0 * wy0 * fz)
          if (vx0 && vy1 && vz0) SEM_ACC(sp0 + DZZ * NC,      w * wx0 * fy  * wz0)
          if (vx0 && vy1 && vz1) SEM_ACC(sp0 + DZZ * NC + NC, w * wx0 * fy  * fz)
          if (vx1 && vy0 && vz0) SEM_ACC(sp1,                 w * fx  * wy0 * wz0)
          if (vx1 && vy0 && vz1) SEM_ACC(sp1 + NC,            w * fx  * wy0 * fz)
          if (vx1 && vy1 && vz0) SEM_ACC(sp1 + DZZ * NC,      w * fx  * fy  * wz0)
          if (vx1 && vy1 && vz1) SEM_ACC(sp1 + DZZ * NC + NC, w * fx  * fy  * fz)
        }
#undef SEM_ACC
      }
    }

    // ---- phase G: wave reductions + per-ray epilogue -> binned atomics ----
    float r0 = sum_bi, r1 = sum_w2, r2 = pkcf;
#pragma unroll
    for (int off = 32; off >= 1; off >>= 1) {
      r0 += __shfl_xor(r0, off);
      r1 += __shfl_xor(r1, off);
      r2 += __shfl_xor(r2, off);
#pragma unroll
      for (int j = 0; j < NC; j++) out_sem[j] += __shfl_xor(out_sem[j], off);
    }
    if (lane == 0) {
      float M = out_sem[0];
#pragma unroll
      for (int j = 1; j < NC; j++) M = fmaxf(M, out_sem[j]);
      float se = 0.f;
#pragma unroll
      for (int j = 0; j < NC; j++) se += expf(out_sem[j] - M);
      float lse = M + logf(se);
      float sy = 0.f;
#pragma unroll
      for (int j = 0; j < NC; j++) if (j == ysem) sy = out_sem[j];
      float nll = lse - sy;
      float cw = (float)(1.0 / log(c_freq[ysem] + 0.001));
      float p = fminf(fmaxf(carry, 1e-6f), 1.0f - 1e-6f);
      float ent = -(p * logf(p) + (1.f - p) * logf(1.f - p));
      float* bin = acc_g + (ray & (NBINS - 1)) * BINSTRIDE;
      atomicAdd(&bin[0], cw * nll);
      atomicAdd(&bin[1], cw);
      atomicAdd(&bin[2], ent);
      atomicAdd(&bin[3], 1.f);
      atomicAdd(&bin[4], r0);
      atomicAdd(&bin[5], r1);
      atomicAdd(&bin[6], r2);
    }
  }

  // ---- fused finalize: last block to finish computes the outputs ----
  if (lane == 0) {
    __threadfence();  // my bin atomics visible before counter increment
    int prev = atomicAdd((int*)acc_g + CNT_OFF, 1);
    if (prev == (int)gridDim.x - 1) {
      float t[7];
#pragma unroll
      for (int j = 0; j < 7; j++) t[j] = 0.f;
#pragma unroll
      for (int b = 0; b < NBINS; b++) {
        float* p = acc_g + b * BINSTRIDE;
#pragma unroll
        for (int j = 0; j < 7; j++) t[j] += atomicAdd(&p[j], 0.f);  // coherent read
      }
      float ls = t[0] / fmaxf(t[1], 1e-12f);
      float nv = fmaxf(t[3], 1.f);
      float le = t[2] / nv;
      float nmax = fmaxf(t[6], 1.f);
      float ld = (t[4] + (1.f / 3.f) * (1.f / nmax) * t[5]) / nv;
      out[0] = 1.0f * ls;    // W_SEM
      out[1] = 0.01f * le;   // W_ENT
      out[2] = 0.01f * ld;   // W_DIST
    }
  }
}

extern "C" void kernel_launch(void* const* d_in, const int* in_sizes, int n_in,
                              void* d_out, int out_size, void* d_ws, size_t ws_size,
                              hipStream_t stream) {
  const float* density = (const float*)d_in[0];
  const float* semantic = (const float*)d_in[1];
  const float* rays = (const float*)d_in[2];
  const float* bda = (const float*)d_in[3];
  float* out = (float*)d_out;
  float* acc = (float*)d_ws;
  int nrays = in_sizes[2] / 10;
  // zero bins (128 floats) + done-counter (int at byte 512): 516 bytes
  hipMemsetAsync(d_ws, 0, 516, stream);
  nerf_main<<<nrays, 64, 0, stream>>>(density, semantic, rays, bda, acc, out,
                                      nrays);
}

// Round 14
// 323.092 us; speedup vs baseline: 1.1738x; 1.1738x over previous
//
#include <hip/hip_runtime.h>
#include <math.h>

// NerfHead: fused ray-march + trilinear + online transmittance + 3 losses.
// R13 = R1's measured-best main body (234us: 4-wave blocks, VGPR 48, block
//       s_acc pre-reduction, flat SEM_ACC gather) + ballot-C (HW-verified
//       bit-exact, replaces 416-step serial scan) + FENCE-FREE fused finalize.
// R12 lesson: __threadfence() per block = device-scope cache invalidate
//   (buffer_inv/wbl2) -> 8192 invalidations kept L1/L2 cold for concurrent
//   gather waves (main 248->330, VALUBusy 27->21, FETCH unchanged).
//   Replacement: s_waitcnt vmcnt(0) before the counter atomic — bin atomicAdds
//   are device-scope and complete at the coherent point; completion (vmcnt
//   drain) = visibility. No cache invalidation.
// Packaging: hipMemsetAsync(516B) + ONE kernel = 2 queue ops (~24us each
//   measured) vs R1's 3 kernels (~71us overhead).
// d_ws: floats [0..6] = accumulators; int at idx 128 (byte 512) = counter.

#define DXX 200
#define DYY 200
#define DZZ 16
#define NC 17
#define S_TOT 416
#define N_IN 390
#define CHUNKS 7
#define RPB 4         // rays (waves) per block
#define CNT_OFF 128   // int index of done-counter (byte 512)

typedef float v4u __attribute__((ext_vector_type(4), aligned(4), may_alias));
typedef float v2u __attribute__((ext_vector_type(2), aligned(4), may_alias));

__constant__ double c_freq[NC] = {1163161.0, 2309034.0, 188743.0, 2997643.0,
  20317180.0, 852476.0, 243808.0, 2457947.0, 497017.0, 2731022.0, 7224789.0,
  214411435.0, 5565043.0, 63191967.0, 76098082.0, 128860031.0, 141625221.0};

__device__ __forceinline__ float iscan_add(float x, int lane) {
#pragma unroll
  for (int off = 1; off < 64; off <<= 1) {
    float y = __shfl_up(x, off);
    if (lane >= off) x += y;
  }
  return x;
}
__device__ __forceinline__ float iscan_mul(float x, int lane) {
#pragma unroll
  for (int off = 1; off < 64; off <<= 1) {
    float y = __shfl_up(x, off);
    if (lane >= off) x *= y;
  }
  return x;
}

__global__ __launch_bounds__(256) void nerf_main(
    const float* __restrict__ density,
    const float* __restrict__ semantic,
    const float* __restrict__ rays,
    const float* __restrict__ bda,
    float* __restrict__ acc_g,
    float* __restrict__ out,
    int nrays) {
  __shared__ float s_t[CHUNKS * 64];
  __shared__ float s_dist[RPB][S_TOT];
  __shared__ unsigned long long s_keep[RPB][CHUNKS];
  __shared__ unsigned long long s_big[RPB][CHUNKS];
  __shared__ float s_acc[8];

  const int lane = threadIdx.x & 63;
  const int wv = threadIdx.x >> 6;
  const int ray = blockIdx.x * RPB + wv;

  // ---- constants matching the reference's numpy derivations ----
  const double BG = (double)(1.0f / 39.0f);
  const float BGf = (float)BG;
  const float DTH = (float)((2.0 + 2.0 * BG) / 200.0 * 0.5 * 0.95);
  const float xminf = (float)(-1.0 - BG);
  const float zf = 6.4f / 80.0f;
  const float sxy = 199.0f / ((float)(1.0 + BG) - xminf);
  const float szc = 15.0f / (zf + zf);
  const float ACTS = -13.815509557964274f;

  if (threadIdx.x < 8) s_acc[threadIdx.x] = 0.f;

  // ---- t table (shared by all rays; computed once per block) ----
  for (int i = threadIdx.x; i < CHUNKS * 64; i += 256) {
    double td;
    if (i < N_IN) {
      td = (2.0 * i + 1.0) / 390.0;
    } else {
      int j = i - N_IN;
      const double stp = (1.0 / 64.0 - 1.0) / 26.0;
      double l0 = 1.0 + j * stp;
      double l1 = (j + 1 >= 26) ? (1.0 / 64.0) : (1.0 + (j + 1) * stp);
      td = 1.0 / l0 + 1.0 / l1;
    }
    s_t[i] = (float)td;
  }
  __syncthreads();

  bool doit = false;
  float rox = 0, roy = 0, roz = 0, rdx = 0, rdy = 0, rdz = 0;
  float b00 = 0, b01 = 0, b02 = 0, b10 = 0, b11 = 0, b12 = 0, b20 = 0, b21 = 0, b22 = 0;
  int ysem = 0;
  if (ray < nrays) {
    const float* rp = rays + (size_t)ray * 10;
    float dep = rp[2];
    doit = (dep > 0.f) && (dep <= 52.f);
    ysem = (int)rp[3];
    ysem = ysem < 0 ? 0 : (ysem > NC - 1 ? NC - 1 : ysem);
    const float czc = (-1.0f + 5.4f) * 0.5f;
    rox = rp[4] / 39.0f;
    roy = rp[5] / 39.0f;
    roz = (rp[6] - czc) / 39.0f;
    float d0 = rp[7], d1 = rp[8], d2 = rp[9];
    float rn = sqrtf(d0 * d0 + d1 * d1 + d2 * d2);
    rdx = d0 / rn; rdy = d1 / rn; rdz = d2 / rn;
    b00 = bda[0]; b01 = bda[1]; b02 = bda[2];
    b10 = bda[3]; b11 = bda[4]; b12 = bda[5];
    b20 = bda[6]; b21 = bda[7]; b22 = bda[8];
  }

  // pts at sample s (after squash + bda); inner flag uses pre-squash norm
  auto compute_pt = [&](int s, float& tx, float& ty, float& tz, float& tt,
                        bool& inner) {
    tt = s_t[s];
    float qx = rox + rdx * tt;
    float qy = roy + rdy * tt;
    float qz = roz + rdz * tt;
    float nr = sqrtf(qx * qx + qy * qy + qz * qz);
    inner = (nr <= 1.0f) && (s < S_TOT);
    if (nr > 1.0f) {
      float sc = (1.0f + BGf - BGf / nr) / nr;
      qx *= sc; qy *= sc; qz *= sc;
    }
    tx = b00 * qx + b01 * qy + b02 * qz;
    ty = b10 * qx + b11 * qy + b12 * qz;
    tz = b20 * qx + b21 * qy + b22 * qz;
  };

  // ---- phase A/B: pts, inner+big ballots, consecutive distances -> LDS ----
  if (doit) {
    for (int c = 0; c < CHUNKS; c++) {
      int s = c * 64 + lane;
      float tx, ty, tz, tt; bool inner;
      compute_pt(s, tx, ty, tz, tt, inner);
      unsigned long long bal = __ballot(inner);
      float nx = __shfl(tx, lane + 1);
      float ny = __shfl(ty, lane + 1);
      float nz = __shfl(tz, lane + 1);
      if (c < CHUNKS - 1) {
        // first sample of next chunk, computed uniformly by all lanes
        float hx, hy, hz, ht; bool hi;
        compute_pt((c + 1) * 64, hx, hy, hz, ht, hi);
        if (lane == 63) { nx = hx; ny = hy; nz = hz; }
      }
      float ex = nx - tx, ey = ny - ty, ez = nz - tz;
      float dd = sqrtf(ex * ex + ey * ey + ez * ez);
      bool dlive = (s < S_TOT - 1);
      if (dlive) s_dist[wv][s] = dd;
      unsigned long long db = __ballot(dlive && (dd > DTH));
      if (lane == 0) { s_keep[wv][c] = bal; s_big[wv][c] = db; }
    }
  }
  __syncthreads();

  // ---- phase C: resetting distance scan, serial ONLY over non-big steps.
  // big step (dist > DTH) forces over=1, cum=0 regardless of incoming cum
  // (f32 add of non-negatives is monotone) -> bit-exact decomposition.
  if (doit && lane == 0) {
    float cum = 0.f;
    int prev = 0;
    unsigned long long carrybit = 0;
#pragma unroll
    for (int c = 0; c < CHUNKS; c++) {
      unsigned long long inner = s_keep[wv][c];
      unsigned long long db = s_big[wv][c];
      unsigned long long big = (db << 1) | carrybit;
      carrybit = db >> 63;
      unsigned long long vmask = ~0ull;
      if (c == 0) vmask &= ~1ull;                       // s=0 is not a step
      if (c == CHUNKS - 1) vmask &= 0x00000000FFFFFFFFull;  // s<=415
      big &= vmask;
      unsigned long long k = inner | big;
      unsigned long long nb = vmask & ~big;
      while (nb) {
        int b = __ffsll((unsigned long long)nb) - 1;
        nb &= nb - 1;
        int s = c * 64 + b;
        if (s - 1 != prev) cum = 0.f;   // gap => previous step was big (reset)
        cum += s_dist[wv][s - 1];
        if (cum > DTH) { cum = 0.f; k |= 1ull << b; }
        prev = s;
      }
      s_keep[wv][c] = k;
    }
  }
  __syncthreads();

  // ---- phase D/E/F: density->alpha, scans, semantic accumulation ----
  if (doit) {
    float out_sem[NC];
#pragma unroll
    for (int j = 0; j < NC; j++) out_sem[j] = 0.f;
    float carry = 1.f, carryW = 0.f, carryWM = 0.f;
    float sum_bi = 0.f, sum_w2 = 0.f, pkcf = 0.f;

    for (int c = 0; c < CHUNKS; c++) {
      unsigned long long km = s_keep[wv][c];
      if (km == 0ull) continue;   // exact identity: a==0 => carries unchanged
      int s = c * 64 + lane;
      float tx, ty, tz, tt; bool inner;
      compute_pt(s, tx, ty, tz, tt, inner);
      float m_ = 1.0f - 1.0f / (1.0f + tt);
      bool keep = (km >> lane) & 1ull;

      int ix = 0, iy = 0, iz = 0;
      float fx = 0.f, fy = 0.f, fz = 0.f;
      float a = 0.f;
      if (keep) {
        float gx = (tx - xminf) * sxy;
        float gy = (ty - xminf) * sxy;
        float gz = (tz + zf) * szc;
        float hx = floorf(gx), hy = floorf(gy), hz = floorf(gz);
        ix = (int)hx; iy = (int)hy; iz = (int)hz;
        fx = gx - hx; fy = gy - hy; fz = gz - hz;
        float wx0 = 1.f - fx, wy0 = 1.f - fy, wz0 = 1.f - fz;
        bool vx0 = (unsigned)ix < (unsigned)DXX, vx1 = (unsigned)(ix + 1) < (unsigned)DXX;
        bool vy0 = (unsigned)iy < (unsigned)DYY, vy1 = (unsigned)(iy + 1) < (unsigned)DYY;
        bool vz0 = (unsigned)iz < (unsigned)DZZ, vz1 = (unsigned)(iz + 1) < (unsigned)DZZ;
        float dens = 0.f;
        if (vx0 && vy0 && vz0) dens += wx0 * wy0 * wz0 * density[((size_t)ix * DYY + iy) * DZZ + iz];
        if (vx0 && vy0 && vz1) dens += wx0 * wy0 * fz  * density[((size_t)ix * DYY + iy) * DZZ + iz + 1];
        if (vx0 && vy1 && vz0) dens += wx0 * fy  * wz0 * density[((size_t)ix * DYY + (iy + 1)) * DZZ + iz];
        if (vx0 && vy1 && vz1) dens += wx0 * fy  * fz  * density[((size_t)ix * DYY + (iy + 1)) * DZZ + iz + 1];
        if (vx1 && vy0 && vz0) dens += fx  * wy0 * wz0 * density[((size_t)(ix + 1) * DYY + iy) * DZZ + iz];
        if (vx1 && vy0 && vz1) dens += fx  * wy0 * fz  * density[((size_t)(ix + 1) * DYY + iy) * DZZ + iz + 1];
        if (vx1 && vy1 && vz0) dens += fx  * fy  * wz0 * density[((size_t)(ix + 1) * DYY + (iy + 1)) * DZZ + iz];
        if (vx1 && vy1 && vz1) dens += fx  * fy  * fz  * density[((size_t)(ix + 1) * DYY + (iy + 1)) * DZZ + iz + 1];
        float u = expf(dens + ACTS);
        a = -expm1f(-0.5f * log1pf(u));   // 1-(1+u)^-0.5, no cancellation
        if (!(a > 1e-7f)) a = 0.f;
      }

      // transmittance cumprod (chunked scan + carry)
      float om = 1.f - a;
      float ip = iscan_mul(om, lane);
      float ex = __shfl_up(ip, 1); if (lane == 0) ex = 1.f;
      float wgt = a * carry * ex;
      carry *= __shfl(ip, 63);
      float w = (wgt > 1e-7f) ? wgt : 0.f;
      if (w > 0.f) pkcf += 1.f;

      // distortion-loss cumsums (exclusive)
      float wm = w * m_;
      float isw = iscan_add(w, lane);
      float iswm = iscan_add(wm, lane);
      float exw = __shfl_up(isw, 1);  if (lane == 0) exw = 0.f;
      float exwm = __shfl_up(iswm, 1); if (lane == 0) exwm = 0.f;
      sum_bi += 2.f * w * (m_ * (carryW + exw) - (carryWM + exwm));
      sum_w2 += w * w;
      carryW += __shfl(isw, 63);
      carryWM += __shfl(iswm, 63);

      // semantic trilinear, only where weight survives
      if (w > 0.f) {
        float wx0 = 1.f - fx, wy0 = 1.f - fy, wz0 = 1.f - fz;
        bool vx0 = (unsigned)ix < (unsigned)DXX, vx1 = (unsigned)(ix + 1) < (unsigned)DXX;
        bool vy0 = (unsigned)iy < (unsigned)DYY, vy1 = (unsigned)(iy + 1) < (unsigned)DYY;
        bool vz0 = (unsigned)iz < (unsigned)DZZ, vz1 = (unsigned)(iz + 1) < (unsigned)DZZ;
#define SEM_CORNER(V, WX, WY, WZ, XI, YI, ZI)                                      \
        if (V) {                                                                    \
          float wc = w * (WX) * (WY) * (WZ);                                        \
          const float* sp = semantic + (((size_t)(XI) * DYY + (YI)) * DZZ + (ZI)) * NC; \
          const v4u* sp4 = (const v4u*)sp;                                          \
          v4u q0 = sp4[0], q1 = sp4[1], q2 = sp4[2], q3 = sp4[3];                   \
          float qs = sp[16];                                                        \
          out_sem[0]  += wc * q0[0];  out_sem[1]  += wc * q0[1];                    \
          out_sem[2]  += wc * q0[2];  out_sem[3]  += wc * q0[3];                    \
          out_sem[4]  += wc * q1[0];  out_sem[5]  += wc * q1[1];                    \
          out_sem[6]  += wc * q1[2];  out_sem[7]  += wc * q1[3];                    \
          out_sem[8]  += wc * q2[0];  out_sem[9]  += wc * q2[1];                    \
          out_sem[10] += wc * q2[2];  out_sem[11] += wc * q2[3];                    \
          out_sem[12] += wc * q3[0];  out_sem[13] += wc * q3[1];                    \
          out_sem[14] += wc * q3[2];  out_sem[15] += wc * q3[3];                    \
          out_sem[16] += wc * qs;                                                   \
        }
        SEM_CORNER(vx0 && vy0 && vz0, wx0, wy0, wz0, ix, iy, iz)
        SEM_CORNER(vx0 && vy0 && vz1, wx0, wy0, fz,  ix, iy, iz + 1)
        SEM_CORNER(vx0 && vy1 && vz0, wx0, fy,  wz0, ix, iy + 1, iz)
        SEM_CORNER(vx0 && vy1 && vz1, wx0, fy,  fz,  ix, iy + 1, iz + 1)
        SEM_CORNER(vx1 && vy0 && vz0, fx,  wy0, wz0, ix + 1, iy, iz)
        SEM_CORNER(vx1 && vy0 && vz1, fx,  wy0, fz,  ix + 1, iy, iz + 1)
        SEM_CORNER(vx1 && vy1 && vz0, fx,  fy,  wz0, ix + 1, iy + 1, iz)
        SEM_CORNER(vx1 && vy1 && vz1, fx,  fy,  fz,  ix + 1, iy + 1, iz + 1)
#undef SEM_CORNER
      }
    }

    // ---- phase G: wave reductions + per-ray epilogue -> block LDS acc ----
    float r0 = sum_bi, r1 = sum_w2, r2 = pkcf;
#pragma unroll
    for (int off = 32; off >= 1; off >>= 1) {
      r0 += __shfl_xor(r0, off);
      r1 += __shfl_xor(r1, off);
      r2 += __shfl_xor(r2, off);
#pragma unroll
      for (int j = 0; j < NC; j++) out_sem[j] += __shfl_xor(out_sem[j], off);
    }
    if (lane == 0) {
      float M = out_sem[0];
#pragma unroll
      for (int j = 1; j < NC; j++) M = fmaxf(M, out_sem[j]);
      float se = 0.f;
#pragma unroll
      for (int j = 0; j < NC; j++) se += expf(out_sem[j] - M);
      float lse = M + logf(se);
      float sy = 0.f;
#pragma unroll
      for (int j = 0; j < NC; j++) if (j == ysem) sy = out_sem[j];
      float nll = lse - sy;
      float cw = (float)(1.0 / log(c_freq[ysem] + 0.001));
      float p = fminf(fmaxf(carry, 1e-6f), 1.0f - 1e-6f);
      float ent = -(p * logf(p) + (1.f - p) * logf(1.f - p));
      atomicAdd(&s_acc[0], cw * nll);
      atomicAdd(&s_acc[1], cw);
      atomicAdd(&s_acc[2], ent);
      atomicAdd(&s_acc[3], 1.f);
      atomicAdd(&s_acc[4], r0);
      atomicAdd(&s_acc[5], r1);
      atomicAdd(&s_acc[6], r2);
    }
  }

  // block-level pre-reduction -> one set of global atomics per block,
  // then fence-free fused finalize (last block computes outputs).
  __syncthreads();
  if (threadIdx.x == 0) {
    if (s_acc[3] > 0.f) {
#pragma unroll
      for (int i = 0; i < 7; i++) atomicAdd(&acc_g[i], s_acc[i]);
    }
    // Wait for MY bin atomics to complete at the device-coherent point.
    // (atomicAdd is device-scope; completion == visibility. No cache
    //  invalidate — R12's __threadfence buffer_inv cost ~80us.)
    asm volatile("s_waitcnt vmcnt(0)" ::: "memory");
    int prev = atomicAdd((int*)acc_g + CNT_OFF, 1);
    if (prev == (int)gridDim.x - 1) {
      float t[7];
#pragma unroll
      for (int j = 0; j < 7; j++) t[j] = atomicAdd(&acc_g[j], 0.f);  // coherent read
      float ls = t[0] / fmaxf(t[1], 1e-12f);
      float nv = fmaxf(t[3], 1.f);
      float le = t[2] / nv;
      float nmax = fmaxf(t[6], 1.f);
      float ld = (t[4] + (1.f / 3.f) * (1.f / nmax) * t[5]) / nv;
      out[0] = 1.0f * ls;    // W_SEM
      out[1] = 0.01f * le;   // W_ENT
      out[2] = 0.01f * ld;   // W_DIST
    }
  }
}

extern "C" void kernel_launch(void* const* d_in, const int* in_sizes, int n_in,
                              void* d_out, int out_size, void* d_ws, size_t ws_size,
                              hipStream_t stream) {
  const float* density = (const float*)d_in[0];
  const float* semantic = (const float*)d_in[1];
  const float* rays = (const float*)d_in[2];
  const float* bda = (const float*)d_in[3];
  float* out = (float*)d_out;
  float* acc = (float*)d_ws;
  int nrays = in_sizes[2] / 10;
  int nb = (nrays + RPB - 1) / RPB;
  // zero accumulators (floats 0..6) + done-counter (int at byte 512)
  hipMemsetAsync(d_ws, 0, 516, stream);
  nerf_main<<<nb, 64 * RPB, 0, stream>>>(density, semantic, rays, bda, acc, out,
                                         nrays);
}